// Round 1
// baseline (649.500 us; speedup 1.0000x reference)
//
#include <hip/hip_runtime.h>

// ---- problem constants (also derived at runtime from in_sizes) ----
#define HBITS 19
#define HSIZE (1u << HBITS)
#define HMASK (HSIZE - 1u)
#define EMPTY_KEY 0xFFFFFFFFu

__device__ __forceinline__ unsigned hash_key(unsigned k) {
    return (k * 2654435761u) >> (32 - HBITS);
}

__device__ __forceinline__ unsigned pack_key(int4 c) {
    // c.x = batch, c.y/z/w = x/y/z, all in [0,256)
    return ((unsigned)c.x << 24) | ((unsigned)c.y << 16) |
           ((unsigned)c.z << 8) | (unsigned)c.w;
}

// Kernel A: insert every voxel key; track min original index per key.
__global__ void build_hash(const int* __restrict__ tgt_coords, int M,
                           unsigned* __restrict__ hkeys, int* __restrict__ hmin) {
    int v = blockIdx.x * blockDim.x + threadIdx.x;
    if (v >= M) return;
    int4 c = ((const int4*)tgt_coords)[v];
    unsigned key = pack_key(c);
    unsigned h = hash_key(key);
    while (true) {
        unsigned prev = atomicCAS(&hkeys[h], EMPTY_KEY, key);
        if (prev == EMPTY_KEY || prev == key) {
            atomicMin(&hmin[h], v);
            break;
        }
        h = (h + 1u) & HMASK;
    }
}

// Kernel B: canonical (min) index for each voxel.
__global__ void canon_lookup(const int* __restrict__ tgt_coords, int M,
                             const unsigned* __restrict__ hkeys,
                             const int* __restrict__ hmin,
                             int* __restrict__ canon) {
    int v = blockIdx.x * blockDim.x + threadIdx.x;
    if (v >= M) return;
    unsigned key = pack_key(((const int4*)tgt_coords)[v]);
    unsigned h = hash_key(key);
    while (hkeys[h] != key) h = (h + 1u) & HMASK;
    canon[v] = hmin[h];
}

// Kernel C: scatter-add point features into canonical voxels.
// 16 threads per point; each handles 4 channels (float4). pfeat reads are
// fully coalesced: global element e reads pfeat4[e].
__global__ void scatter_points(const float4* __restrict__ pfeat4,
                               const int* __restrict__ pts_idx,
                               const int* __restrict__ canon,
                               int BN,
                               float* __restrict__ cnt,
                               float* __restrict__ sums) {
    int e = blockIdx.x * blockDim.x + threadIdx.x;
    if (e >= BN * 16) return;
    int p = e >> 4;
    int sub = e & 15;
    int c = canon[pts_idx[p]];
    float4 f = pfeat4[e];
    float* dst = sums + (size_t)c * 64 + sub * 4;
    atomicAdd(dst + 0, f.x);
    atomicAdd(dst + 1, f.y);
    atomicAdd(dst + 2, f.z);
    atomicAdd(dst + 3, f.w);
    if (sub == 0) atomicAdd(&cnt[c], 1.0f);
}

// Kernel D: out[v,:] = concat(tgt_feats[v], sums[v]/max(cnt,1)) @ W + b
// One thread per (v, oc). W (96x32 = 12 KB) staged in LDS.
// LDS access Ws[k*32+oc]: lanes 0..31 hit distinct banks (2 lanes/bank in
// wave64 — free per m136).
__global__ void fuse_out(const float* __restrict__ tgt_feats,
                         const float* __restrict__ W,
                         const float* __restrict__ bias,
                         const float* __restrict__ cnt,
                         const float* __restrict__ sums,
                         int M,
                         float* __restrict__ out) {
    __shared__ float Ws[96 * 32];
    __shared__ float bs[32];
    for (int i = threadIdx.x; i < 96 * 32; i += blockDim.x) Ws[i] = W[i];
    if (threadIdx.x < 32) bs[threadIdx.x] = bias[threadIdx.x];
    __syncthreads();

    int e = blockIdx.x * blockDim.x + threadIdx.x;
    if (e >= M * 32) return;
    int v = e >> 5;
    int oc = e & 31;

    float inv = 1.0f / fmaxf(cnt[v], 1.0f);
    float acc = bs[oc];

    const float4* tf4 = (const float4*)(tgt_feats + (size_t)v * 32);
#pragma unroll
    for (int k4 = 0; k4 < 8; ++k4) {
        float4 t = tf4[k4];
        acc += t.x * Ws[(k4 * 4 + 0) * 32 + oc];
        acc += t.y * Ws[(k4 * 4 + 1) * 32 + oc];
        acc += t.z * Ws[(k4 * 4 + 2) * 32 + oc];
        acc += t.w * Ws[(k4 * 4 + 3) * 32 + oc];
    }
    const float4* sm4 = (const float4*)(sums + (size_t)v * 64);
#pragma unroll
    for (int k4 = 0; k4 < 16; ++k4) {
        float4 s = sm4[k4];
        acc += (s.x * inv) * Ws[(32 + k4 * 4 + 0) * 32 + oc];
        acc += (s.y * inv) * Ws[(32 + k4 * 4 + 1) * 32 + oc];
        acc += (s.z * inv) * Ws[(32 + k4 * 4 + 2) * 32 + oc];
        acc += (s.w * inv) * Ws[(32 + k4 * 4 + 3) * 32 + oc];
    }
    out[e] = acc;
}

extern "C" void kernel_launch(void* const* d_in, const int* in_sizes, int n_in,
                              void* d_out, int out_size, void* d_ws, size_t ws_size,
                              hipStream_t stream) {
    const float* pfeat      = (const float*)d_in[0];  // (BN, 64)
    const float* tgt_feats  = (const float*)d_in[1];  // (M, 32)
    const float* W_fuse     = (const float*)d_in[2];  // (96, 32)
    const float* b_fuse     = (const float*)d_in[3];  // (32,)
    const int*   tgt_coords = (const int*)d_in[4];    // (M, 4)
    const int*   pts_idx    = (const int*)d_in[5];    // (BN,)
    float* out = (float*)d_out;                       // (M, 32)

    const int M  = in_sizes[4] / 4;
    const int BN = in_sizes[5];

    // workspace layout
    char* ws = (char*)d_ws;
    unsigned* hkeys = (unsigned*)ws;                                   // HSIZE*4
    int*      hmin  = (int*)(ws + (size_t)HSIZE * 4);                  // HSIZE*4
    float*    cnt   = (float*)(ws + (size_t)HSIZE * 8);                // M*4
    float*    sums  = (float*)(ws + (size_t)HSIZE * 8 + (size_t)M * 4);        // M*64*4
    int*      canon = (int*)(ws + (size_t)HSIZE * 8 + (size_t)M * 4
                                + (size_t)M * 64 * 4);                 // M*4

    // re-init every call (ws is poisoned with 0xAA before each timed launch)
    hipMemsetAsync(hkeys, 0xFF, (size_t)HSIZE * 4, stream);            // EMPTY_KEY
    hipMemsetAsync(hmin, 0x7F, (size_t)HSIZE * 4, stream);             // > any index
    hipMemsetAsync(cnt, 0, (size_t)M * 4 + (size_t)M * 64 * 4, stream);// cnt+sums

    const int TB = 256;
    build_hash<<<(M + TB - 1) / TB, TB, 0, stream>>>(tgt_coords, M, hkeys, hmin);
    canon_lookup<<<(M + TB - 1) / TB, TB, 0, stream>>>(tgt_coords, M, hkeys, hmin, canon);
    scatter_points<<<((size_t)BN * 16 + TB - 1) / TB, TB, 0, stream>>>(
        (const float4*)pfeat, pts_idx, canon, BN, cnt, sums);
    fuse_out<<<((size_t)M * 32 + TB - 1) / TB, TB, 0, stream>>>(
        tgt_feats, W_fuse, b_fuse, cnt, sums, M, out);
}

// Round 2
// 332.536 us; speedup vs baseline: 1.9532x; 1.9532x over previous
//
#include <hip/hip_runtime.h>

// ---- hash constants ----
#define HBITS 19
#define HSIZE (1u << HBITS)
#define HMASK (HSIZE - 1u)
#define EMPTY_KEY 0xFFFFFFFFu

__device__ __forceinline__ unsigned hash_key(unsigned k) {
    return (k * 2654435761u) >> (32 - HBITS);
}

__device__ __forceinline__ unsigned pack_key(int4 c) {
    // c.x = batch, c.y/z/w = x/y/z, all in [0,256)
    return ((unsigned)c.x << 24) | ((unsigned)c.y << 16) |
           ((unsigned)c.z << 8) | (unsigned)c.w;
}

// Kernel A: insert every voxel key; track min original index per key.
__global__ void build_hash(const int* __restrict__ tgt_coords, int M,
                           unsigned* __restrict__ hkeys, int* __restrict__ hmin) {
    int v = blockIdx.x * blockDim.x + threadIdx.x;
    if (v >= M) return;
    int4 c = ((const int4*)tgt_coords)[v];
    unsigned key = pack_key(c);
    unsigned h = hash_key(key);
    while (true) {
        unsigned prev = atomicCAS(&hkeys[h], EMPTY_KEY, key);
        if (prev == EMPTY_KEY || prev == key) {
            atomicMin(&hmin[h], v);
            break;
        }
        h = (h + 1u) & HMASK;
    }
}

// Kernel B: canonical (min) index for each voxel.
__global__ void canon_lookup(const int* __restrict__ tgt_coords, int M,
                             const unsigned* __restrict__ hkeys,
                             const int* __restrict__ hmin,
                             int* __restrict__ canon) {
    int v = blockIdx.x * blockDim.x + threadIdx.x;
    if (v >= M) return;
    unsigned key = pack_key(((const int4*)tgt_coords)[v]);
    unsigned h = hash_key(key);
    while (hkeys[h] != key) h = (h + 1u) & HMASK;
    canon[v] = hmin[h];
}

// Kernel L: build per-canonical-voxel linked list of points.
// 400k atomicExch total (vs 25.6M fp32 atomicAdd before).
__global__ void link_points(const int* __restrict__ pts_idx,
                            const int* __restrict__ canon, int BN,
                            int* __restrict__ head, int* __restrict__ next) {
    int p = blockIdx.x * blockDim.x + threadIdx.x;
    if (p >= BN) return;
    int c = canon[pts_idx[p]];
    int old = atomicExch(&head[c], p);
    next[p] = old;
}

// Kernel F: per voxel, walk the point list (32 lanes cooperatively, each lane
// owns 2 of the 64 img channels), compute mean, then fused
// out[v,:] = concat(tgt_feats[v], mean[v]) @ W + b via LDS-staged W.
#define VPB 8  // voxels per 256-thread block (32 lanes per voxel)
__global__ void fuse_gather(const float2* __restrict__ pf2,     // (BN,64) viewed as (BN,32) float2
                            const int* __restrict__ head,
                            const int* __restrict__ next,
                            const float* __restrict__ tgt_feats,
                            const float* __restrict__ W,
                            const float* __restrict__ bias,
                            int M,
                            float* __restrict__ out) {
    __shared__ float Ws[96 * 32];
    __shared__ float bs[32];
    __shared__ __align__(16) float xbuf[VPB][96];  // row = 384 B, 16B-aligned

    int t = threadIdx.x;
    for (int i = t; i < 96 * 32; i += 256) Ws[i] = W[i];
    if (t < 32) bs[t] = bias[t];

    int grp = t >> 5;   // 0..7
    int g   = t & 31;   // lane within group
    int v = blockIdx.x * VPB + grp;
    bool valid = v < M;

    // ---- gather-mean: walk list, coalesced float2 row reads ----
    float sx = 0.0f, sy = 0.0f;
    int c = 0;
    int p = valid ? head[v] : -1;
    while (p >= 0) {
        float2 f = pf2[(size_t)p * 32 + g];
        sx += f.x; sy += f.y;
        ++c;
        p = next[p];  // broadcast load (all 32 lanes same address)
    }
    float inv = 1.0f / fmaxf((float)c, 1.0f);

    if (valid) {
        xbuf[grp][32 + 2 * g]     = sx * inv;
        xbuf[grp][32 + 2 * g + 1] = sy * inv;
        if (g < 16) {
            float2 tf = ((const float2*)tgt_feats)[(size_t)v * 16 + g];
            xbuf[grp][2 * g]     = tf.x;
            xbuf[grp][2 * g + 1] = tf.y;
        }
    }
    __syncthreads();
    if (!valid) return;

    // ---- matmul: lane g computes out[v][g] ----
    // Ws[k*32+g]: lanes 0-31 consecutive banks, lanes 32-63 same addrs (broadcast) — free.
    // xbuf reads: 32-lane same-address broadcast ds_read_b128 — free.
    float acc = bs[g];
#pragma unroll
    for (int k4 = 0; k4 < 24; ++k4) {
        float4 x = *(const float4*)&xbuf[grp][k4 * 4];
        acc = fmaf(x.x, Ws[(k4 * 4 + 0) * 32 + g], acc);
        acc = fmaf(x.y, Ws[(k4 * 4 + 1) * 32 + g], acc);
        acc = fmaf(x.z, Ws[(k4 * 4 + 2) * 32 + g], acc);
        acc = fmaf(x.w, Ws[(k4 * 4 + 3) * 32 + g], acc);
    }
    out[(size_t)v * 32 + g] = acc;
}

extern "C" void kernel_launch(void* const* d_in, const int* in_sizes, int n_in,
                              void* d_out, int out_size, void* d_ws, size_t ws_size,
                              hipStream_t stream) {
    const float* pfeat      = (const float*)d_in[0];  // (BN, 64)
    const float* tgt_feats  = (const float*)d_in[1];  // (M, 32)
    const float* W_fuse     = (const float*)d_in[2];  // (96, 32)
    const float* b_fuse     = (const float*)d_in[3];  // (32,)
    const int*   tgt_coords = (const int*)d_in[4];    // (M, 4)
    const int*   pts_idx    = (const int*)d_in[5];    // (BN,)
    float* out = (float*)d_out;                       // (M, 32)

    const int M  = in_sizes[4] / 4;
    const int BN = in_sizes[5];

    // workspace layout (all small: ~7.2 MB total)
    char* ws = (char*)d_ws;
    unsigned* hkeys = (unsigned*)ws;                                    // HSIZE*4 = 2 MB
    int*      hmin  = (int*)(ws + (size_t)HSIZE * 4);                   // 2 MB
    int*      canon = (int*)(ws + (size_t)HSIZE * 8);                   // M*4
    int*      head  = (int*)(ws + (size_t)HSIZE * 8 + (size_t)M * 4);   // M*4
    int*      next  = (int*)(ws + (size_t)HSIZE * 8 + (size_t)M * 8);   // BN*4

    hipMemsetAsync(hkeys, 0xFF, (size_t)HSIZE * 4, stream);  // EMPTY_KEY
    hipMemsetAsync(hmin, 0x7F, (size_t)HSIZE * 4, stream);   // > any index
    hipMemsetAsync(head, 0xFF, (size_t)M * 4, stream);       // -1 (empty list)

    const int TB = 256;
    build_hash<<<(M + TB - 1) / TB, TB, 0, stream>>>(tgt_coords, M, hkeys, hmin);
    canon_lookup<<<(M + TB - 1) / TB, TB, 0, stream>>>(tgt_coords, M, hkeys, hmin, canon);
    link_points<<<(BN + TB - 1) / TB, TB, 0, stream>>>(pts_idx, canon, BN, head, next);
    fuse_gather<<<(M + VPB - 1) / VPB, TB, 0, stream>>>(
        (const float2*)pfeat, head, next, tgt_feats, W_fuse, b_fuse, M, out);
}

// Round 3
// 313.056 us; speedup vs baseline: 2.0747x; 1.0622x over previous
//
#include <hip/hip_runtime.h>

// ---- hash / bucket constants ----
#define HBITS 19
#define HSIZE (1u << HBITS)
#define HMASK (HSIZE - 1u)
#define EMPTY_KEY 0xFFFFFFFFu
#define SLOTS 8   // direct slots per voxel; overflow (P~1e-4) goes to chain

__device__ __forceinline__ unsigned hash_key(unsigned k) {
    return (k * 2654435761u) >> (32 - HBITS);
}

__device__ __forceinline__ unsigned pack_key(int4 c) {
    // c.x = batch (<4), c.y/z/w = xyz in [0,256)
    return ((unsigned)c.x << 24) | ((unsigned)c.y << 16) |
           ((unsigned)c.z << 8) | (unsigned)c.w;
}

// Kernel A: insert voxel keys; htab[h] = (key, min original index).
__global__ __launch_bounds__(256)
void build_hash(const int4* __restrict__ tgt_coords, int M,
                uint2* __restrict__ htab) {
    int v = blockIdx.x * blockDim.x + threadIdx.x;
    if (v >= M) return;
    unsigned key = pack_key(tgt_coords[v]);
    unsigned h = hash_key(key);
    while (true) {
        unsigned prev = atomicCAS(&htab[h].x, EMPTY_KEY, key);
        if (prev == EMPTY_KEY || prev == key) {
            atomicMin(&htab[h].y, (unsigned)v);   // canonical = min index
            break;
        }
        h = (h + 1u) & HMASK;
    }
}

// Kernel B: each point probes the hash for its canonical voxel and claims a
// bucket slot. cnt[] init = -1 (0xFF memset) so atomicAdd+1 gives slot 0,1,...
__global__ __launch_bounds__(256)
void fill_slots(const int* __restrict__ pts_idx,
                const int4* __restrict__ tgt_coords,
                const uint2* __restrict__ htab,
                int BN,
                int* __restrict__ cnt,      // (M) init -1
                int* __restrict__ slotbuf,  // (M*SLOTS) no init needed
                int* __restrict__ ohead,    // (M) init -1
                int* __restrict__ nxt) {    // (BN) no init needed
    int p = blockIdx.x * blockDim.x + threadIdx.x;
    if (p >= BN) return;
    int vox = pts_idx[p];
    unsigned key = pack_key(tgt_coords[vox]);
    unsigned h = hash_key(key);
    uint2 e = htab[h];
    while (e.x != key) { h = (h + 1u) & HMASK; e = htab[h]; }
    int c = (int)e.y;
    int idx = atomicAdd(&cnt[c], 1) + 1;
    if (idx < SLOTS) slotbuf[c * SLOTS + idx] = p;
    else             nxt[p] = atomicExch(&ohead[c], p);   // rare
}

// Kernel C: per voxel (32 lanes), gather & mean point rows from bucket slots
// (all row loads independent -> overlapped), then fused matmul
// out[v,:] = concat(tgt_feats[v], mean[v]) @ W + b with LDS-staged W.
#define VPB 8
__global__ __launch_bounds__(256)
void fuse_bucket(const float2* __restrict__ pf2,   // (BN,64) as (BN,32) float2
                 const int* __restrict__ cnt,
                 const int4* __restrict__ slot4,   // slotbuf viewed as (M,2) int4
                 const int* __restrict__ ohead,
                 const int* __restrict__ nxt,
                 const float* __restrict__ tgt_feats,
                 const float* __restrict__ W,
                 const float* __restrict__ bias,
                 int M,
                 float* __restrict__ out) {
    __shared__ float Ws[96 * 32];
    __shared__ float bs[32];
    __shared__ __align__(16) float xbuf[VPB][96];

    int t = threadIdx.x;
    for (int i = t; i < 96 * 32; i += 256) Ws[i] = W[i];
    if (t < 32) bs[t] = bias[t];

    int grp = t >> 5;
    int g   = t & 31;
    int v = blockIdx.x * VPB + grp;
    bool valid = v < M;

    float sx = 0.0f, sy = 0.0f;
    int n = 0;
    if (valid) {
        n = cnt[v] + 1;
        // load slot indices up-front (2 independent 16B broadcast loads)
        int4 sa = make_int4(0, 0, 0, 0), sb = make_int4(0, 0, 0, 0);
        if (n > 0) sa = slot4[(size_t)v * 2];
        if (n > 4) sb = slot4[(size_t)v * 2 + 1];
        // issue all row loads before accumulating (independent, overlap)
        float2 f0 = {0,0}, f1 = {0,0}, f2 = {0,0}, f3 = {0,0};
        float2 f4 = {0,0}, f5 = {0,0}, f6 = {0,0}, f7 = {0,0};
        if (n > 0) f0 = pf2[(size_t)sa.x * 32 + g];
        if (n > 1) f1 = pf2[(size_t)sa.y * 32 + g];
        if (n > 2) f2 = pf2[(size_t)sa.z * 32 + g];
        if (n > 3) f3 = pf2[(size_t)sa.w * 32 + g];
        if (n > 4) f4 = pf2[(size_t)sb.x * 32 + g];
        if (n > 5) f5 = pf2[(size_t)sb.y * 32 + g];
        if (n > 6) f6 = pf2[(size_t)sb.z * 32 + g];
        if (n > 7) f7 = pf2[(size_t)sb.w * 32 + g];
        sx = ((f0.x + f1.x) + (f2.x + f3.x)) + ((f4.x + f5.x) + (f6.x + f7.x));
        sy = ((f0.y + f1.y) + (f2.y + f3.y)) + ((f4.y + f5.y) + (f6.y + f7.y));
        if (n > SLOTS) {  // extremely rare overflow chain
            int p = ohead[v];
            while (p >= 0) {
                float2 f = pf2[(size_t)p * 32 + g];
                sx += f.x; sy += f.y;
                p = nxt[p];
            }
        }
    }
    float inv = 1.0f / fmaxf((float)n, 1.0f);

    if (valid) {
        xbuf[grp][32 + 2 * g]     = sx * inv;
        xbuf[grp][32 + 2 * g + 1] = sy * inv;
        if (g < 16) {
            float2 tf = ((const float2*)tgt_feats)[(size_t)v * 16 + g];
            xbuf[grp][2 * g]     = tf.x;
            xbuf[grp][2 * g + 1] = tf.y;
        }
    }
    __syncthreads();
    if (!valid) return;

    float acc = bs[g];
#pragma unroll
    for (int k4 = 0; k4 < 24; ++k4) {
        float4 x = *(const float4*)&xbuf[grp][k4 * 4];
        acc = fmaf(x.x, Ws[(k4 * 4 + 0) * 32 + g], acc);
        acc = fmaf(x.y, Ws[(k4 * 4 + 1) * 32 + g], acc);
        acc = fmaf(x.z, Ws[(k4 * 4 + 2) * 32 + g], acc);
        acc = fmaf(x.w, Ws[(k4 * 4 + 3) * 32 + g], acc);
    }
    out[(size_t)v * 32 + g] = acc;
}

extern "C" void kernel_launch(void* const* d_in, const int* in_sizes, int n_in,
                              void* d_out, int out_size, void* d_ws, size_t ws_size,
                              hipStream_t stream) {
    const float* pfeat      = (const float*)d_in[0];  // (BN,64)
    const float* tgt_feats  = (const float*)d_in[1];  // (M,32)
    const float* W_fuse     = (const float*)d_in[2];  // (96,32)
    const float* b_fuse     = (const float*)d_in[3];  // (32,)
    const int*   tgt_coords = (const int*)d_in[4];    // (M,4)
    const int*   pts_idx    = (const int*)d_in[5];    // (BN,)
    float* out = (float*)d_out;                       // (M,32)

    const int M  = in_sizes[4] / 4;
    const int BN = in_sizes[5];

    // workspace: [htab 4MB | cnt M | ohead M]  <- single 0xFF memset region
    //            [slotbuf M*8 | nxt BN]        <- write-before-read, no init
    char* ws = (char*)d_ws;
    uint2* htab    = (uint2*)ws;
    int*   cnt     = (int*)(ws + (size_t)HSIZE * 8);
    int*   ohead   = (int*)(ws + (size_t)HSIZE * 8 + (size_t)M * 4);
    int*   slotbuf = (int*)(ws + (size_t)HSIZE * 8 + (size_t)M * 8);
    int*   nxt     = (int*)(ws + (size_t)HSIZE * 8 + (size_t)M * 8 + (size_t)M * SLOTS * 4);

    size_t ff_bytes = (size_t)HSIZE * 8 + (size_t)M * 8;
    hipMemsetAsync(htab, 0xFF, ff_bytes, stream);  // EMPTY_KEY / UINT_MAX / -1 / -1

    const int TB = 256;
    build_hash<<<(M + TB - 1) / TB, TB, 0, stream>>>(
        (const int4*)tgt_coords, M, htab);
    fill_slots<<<(BN + TB - 1) / TB, TB, 0, stream>>>(
        pts_idx, (const int4*)tgt_coords, htab, BN, cnt, slotbuf, ohead, nxt);
    fuse_bucket<<<(M + VPB - 1) / VPB, TB, 0, stream>>>(
        (const float2*)pfeat, cnt, (const int4*)slotbuf, ohead, nxt,
        tgt_feats, W_fuse, b_fuse, M, out);
}